// Round 2
// baseline (770.684 us; speedup 1.0000x reference)
//
#include <hip/hip_runtime.h>

#define BB 4
#define NN 4096
#define DD 256
#define PP 64
#define HH 1024
#define NCC 256
#define TOPK 8

// ---------------------------------------------------------------------------
// K1: Q = A@Wq+bq, K = A@Wk+bk, proj = A@Wc+bc, pn = proj/max(||proj||,1e-12)
// ---------------------------------------------------------------------------
__global__ __launch_bounds__(256) void k_proj(
    const float* __restrict__ act,
    const float* __restrict__ Wq, const float* __restrict__ bq,
    const float* __restrict__ Wk, const float* __restrict__ bk,
    const float* __restrict__ Wc, const float* __restrict__ bc,
    float* __restrict__ Qo, float* __restrict__ Ko, float* __restrict__ PNo)
{
    __shared__ float As[16][DD];   // 16KB
    __shared__ float Ps[16][PP];   // 4KB
    const int tid = threadIdx.x;
    const long row0 = (long)blockIdx.x * 16;

    {
        const float4* g4 = (const float4*)(act + row0 * DD);
        float4* s4 = (float4*)(&As[0][0]);
#pragma unroll
        for (int i = 0; i < 4; ++i) s4[tid + i * 256] = g4[tid + i * 256];
    }
    __syncthreads();

    const int col = tid & 63;
    const int rg  = tid >> 6;   // 0..3 -> rows rg*4+j
    float aq[4], ak[4], ac[4];
#pragma unroll
    for (int j = 0; j < 4; ++j) { aq[j] = bq[col]; ak[j] = bk[col]; ac[j] = bc[col]; }

    for (int d = 0; d < DD; ++d) {
        float wq = Wq[d * PP + col];
        float wk = Wk[d * PP + col];
        float wc = Wc[d * PP + col];
#pragma unroll
        for (int j = 0; j < 4; ++j) {
            float a = As[rg * 4 + j][d];
            aq[j] = fmaf(a, wq, aq[j]);
            ak[j] = fmaf(a, wk, ak[j]);
            ac[j] = fmaf(a, wc, ac[j]);
        }
    }
#pragma unroll
    for (int j = 0; j < 4; ++j) {
        long r = row0 + rg * 4 + j;
        Qo[r * PP + col] = aq[j];
        Ko[r * PP + col] = ak[j];
        Ps[rg * 4 + j][col] = ac[j];
    }
    __syncthreads();

    const int w = tid >> 6;
    const int lane = tid & 63;
#pragma unroll
    for (int j = 0; j < 4; ++j) {
        int r = w * 4 + j;
        float v = Ps[r][lane];
        float ss = v * v;
#pragma unroll
        for (int off = 32; off >= 1; off >>= 1) ss += __shfl_xor(ss, off, 64);
        float nrm = fmaxf(sqrtf(ss), 1e-12f);
        PNo[(row0 + r) * PP + lane] = v / nrm;
    }
}

// ---------------------------------------------------------------------------
// K2: scores = Q K^T / 8 -> per-row top-8 -> softmax -> incoming gather.
// float4 LDS reads (ds_read_b128), [128][68] K tile (16B-aligned rows).
// ---------------------------------------------------------------------------
__global__ __launch_bounds__(256) void k_topk(
    const float* __restrict__ Q, const float* __restrict__ K,
    const float* __restrict__ states, float* __restrict__ incoming)
{
    __shared__ float Qs[32][PP];                    // 8KB
    __shared__ union UU {
        float Ks[128][68];                          // 34.8KB, row stride 272B (16B aligned)
        struct MM { float cv[32][256]; unsigned short ci[32][256]; } m;  // 48KB
    } u;

    const int tid = threadIdx.x;
    const int b  = blockIdx.x >> 7;
    const int n0 = (blockIdx.x & 127) << 5;

    {
        const float4* g4 = (const float4*)(Q + ((long)b * NN + n0) * PP);
        float4* s4 = (float4*)(&Qs[0][0]);
        s4[tid] = g4[tid];
        s4[tid + 256] = g4[tid + 256];
    }

    const int mg = tid & 31;        // m sub-index
    const int rg = tid >> 5;        // 0..7 -> rows rg+8j
    float topv[4][TOPK];
    int   topi[4][TOPK];
    float vmin[4];
#pragma unroll
    for (int j = 0; j < 4; ++j) {
        vmin[j] = -1e30f;
#pragma unroll
        for (int t = 0; t < TOPK; ++t) { topv[j][t] = -1e30f; topi[j][t] = 0; }
    }

    for (int mt = 0; mt < NN / 128; ++mt) {
        const int m0 = mt << 7;
        __syncthreads();
        {
            const float4* g4 = (const float4*)(K + ((long)b * NN + m0) * PP);
#pragma unroll
            for (int t = 0; t < 8; ++t) {
                int q = tid + t * 256;                 // 0..2047 float4s
                *(float4*)(&u.Ks[q >> 4][(q & 15) << 2]) = g4[q];
            }
        }
        __syncthreads();

        float s[4][4];
#pragma unroll
        for (int j = 0; j < 4; ++j)
#pragma unroll
            for (int k = 0; k < 4; ++k) s[j][k] = 0.f;

#pragma unroll 2
        for (int p = 0; p < PP; p += 4) {
            float4 qv[4], kv[4];
#pragma unroll
            for (int j = 0; j < 4; ++j) qv[j] = *(const float4*)(&Qs[rg + 8 * j][p]);
#pragma unroll
            for (int k = 0; k < 4; ++k) kv[k] = *(const float4*)(&u.Ks[mg + 32 * k][p]);
#pragma unroll
            for (int j = 0; j < 4; ++j)
#pragma unroll
                for (int k = 0; k < 4; ++k) {
                    s[j][k] = fmaf(qv[j].x, kv[k].x, s[j][k]);
                    s[j][k] = fmaf(qv[j].y, kv[k].y, s[j][k]);
                    s[j][k] = fmaf(qv[j].z, kv[k].z, s[j][k]);
                    s[j][k] = fmaf(qv[j].w, kv[k].w, s[j][k]);
                }
        }

#pragma unroll
        for (int j = 0; j < 4; ++j) {
#pragma unroll
            for (int k = 0; k < 4; ++k) {
                float val = s[j][k] * 0.125f;
                int idx = m0 + mg + 32 * k;
                if (val > vmin[j]) {
                    float mv = topv[j][0];
#pragma unroll
                    for (int t = 1; t < TOPK; ++t) mv = fminf(mv, topv[j][t]);
                    bool done = false;
#pragma unroll
                    for (int t = 0; t < TOPK; ++t) {   // static-index replace
                        bool take = (!done) && (topv[j][t] == mv);
                        if (take) { topv[j][t] = val; topi[j][t] = idx; done = true; }
                    }
                    float nm = topv[j][0];
#pragma unroll
                    for (int t = 1; t < TOPK; ++t) nm = fminf(nm, topv[j][t]);
                    vmin[j] = nm;
                }
            }
        }
    }
    __syncthreads();

    // dump per-thread candidates: row rr gets 32 threads x 8 = 256 candidates
#pragma unroll
    for (int j = 0; j < 4; ++j) {
        int rr = rg + 8 * j;
#pragma unroll
        for (int t = 0; t < TOPK; ++t) {
            u.m.cv[rr][mg * 8 + t] = topv[j][t];
            u.m.ci[rr][mg * 8 + t] = (unsigned short)topi[j][t];
        }
    }
    __syncthreads();

    // merge: wave w handles rows w*8 .. w*8+7
    const int w = tid >> 6;
    const int lane = tid & 63;
    for (int rr = w * 8; rr < w * 8 + 8; ++rr) {
        float v0 = u.m.cv[rr][lane];
        float v1 = u.m.cv[rr][lane + 64];
        float v2 = u.m.cv[rr][lane + 128];
        float v3 = u.m.cv[rr][lane + 192];
        float wv[8]; int wi[8];
#pragma unroll
        for (int e = 0; e < TOPK; ++e) {
            float lv = v0; int ls = 0;
            if (v1 > lv) { lv = v1; ls = 1; }
            if (v2 > lv) { lv = v2; ls = 2; }
            if (v3 > lv) { lv = v3; ls = 3; }
            int slot = ls * 64 + lane;
#pragma unroll
            for (int off = 32; off >= 1; off >>= 1) {
                float ov = __shfl_xor(lv, off, 64);
                int   os = __shfl_xor(slot, off, 64);
                if (ov > lv || (ov == lv && os < slot)) { lv = ov; slot = os; }
            }
            wv[e] = lv;
            wi[e] = (int)u.m.ci[rr][slot];
            if (slot == 0 * 64 + lane) v0 = -1e30f;
            if (slot == 1 * 64 + lane) v1 = -1e30f;
            if (slot == 2 * 64 + lane) v2 = -1e30f;
            if (slot == 3 * 64 + lane) v3 = -1e30f;
        }
        float mx = wv[0];
        float ex[8]; float Z = 0.f;
#pragma unroll
        for (int e = 0; e < TOPK; ++e) { ex[e] = expf(wv[e] - mx); Z += ex[e]; }
        float invZ = 1.0f / Z;

        float ax = 0.f, ay = 0.f, az = 0.f, aw = 0.f;
#pragma unroll
        for (int e = 0; e < TOPK; ++e) {
            const float4* sp = (const float4*)(states + ((long)b * NN + wi[e]) * DD);
            float4 sv = sp[lane];
            float we = ex[e] * invZ;
            ax = fmaf(we, sv.x, ax); ay = fmaf(we, sv.y, ay);
            az = fmaf(we, sv.z, az); aw = fmaf(we, sv.w, aw);
        }
        float4 o; o.x = ax; o.y = ay; o.z = az; o.w = aw;
        ((float4*)(incoming + ((long)b * NN + n0 + rr) * DD))[lane] = o;
    }
}

// ---------------------------------------------------------------------------
// K3: sim = pn pn^T; cmask = sim>0.7; combined; out = 0.8*inc + 0.2*combined
// ---------------------------------------------------------------------------
#define CAP 64
__global__ __launch_bounds__(256) void k_coal(
    const float* __restrict__ PN, const float* __restrict__ incoming,
    float* __restrict__ outs)
{
    __shared__ float Qs[32][PP];        // 8KB
    __shared__ float Ks[128][68];       // 34.8KB
    __shared__ int cnt[32];
    __shared__ unsigned short lst[32][CAP];   // 4KB

    const int tid = threadIdx.x;
    const int b  = blockIdx.x >> 7;
    const int n0 = (blockIdx.x & 127) << 5;

    if (tid < 32) cnt[tid] = 0;
    {
        const float4* g4 = (const float4*)(PN + ((long)b * NN + n0) * PP);
        float4* s4 = (float4*)(&Qs[0][0]);
        s4[tid] = g4[tid];
        s4[tid + 256] = g4[tid + 256];
    }

    const int mg = tid & 31;
    const int rg = tid >> 5;

    for (int mt = 0; mt < NN / 128; ++mt) {
        const int m0 = mt << 7;
        __syncthreads();
        {
            const float4* g4 = (const float4*)(PN + ((long)b * NN + m0) * PP);
#pragma unroll
            for (int t = 0; t < 8; ++t) {
                int q = tid + t * 256;
                *(float4*)(&Ks[q >> 4][(q & 15) << 2]) = g4[q];
            }
        }
        __syncthreads();

        float s[4][4];
#pragma unroll
        for (int j = 0; j < 4; ++j)
#pragma unroll
            for (int k = 0; k < 4; ++k) s[j][k] = 0.f;

#pragma unroll 2
        for (int p = 0; p < PP; p += 4) {
            float4 qv[4], kv[4];
#pragma unroll
            for (int j = 0; j < 4; ++j) qv[j] = *(const float4*)(&Qs[rg + 8 * j][p]);
#pragma unroll
            for (int k = 0; k < 4; ++k) kv[k] = *(const float4*)(&Ks[mg + 32 * k][p]);
#pragma unroll
            for (int j = 0; j < 4; ++j)
#pragma unroll
                for (int k = 0; k < 4; ++k) {
                    s[j][k] = fmaf(qv[j].x, kv[k].x, s[j][k]);
                    s[j][k] = fmaf(qv[j].y, kv[k].y, s[j][k]);
                    s[j][k] = fmaf(qv[j].z, kv[k].z, s[j][k]);
                    s[j][k] = fmaf(qv[j].w, kv[k].w, s[j][k]);
                }
        }

#pragma unroll
        for (int j = 0; j < 4; ++j)
#pragma unroll
            for (int k = 0; k < 4; ++k) {
                if (s[j][k] > 0.7f) {
                    int pos = atomicAdd(&cnt[rg + 8 * j], 1);
                    if (pos < CAP) lst[rg + 8 * j][pos] = (unsigned short)(m0 + mg + 32 * k);
                }
            }
    }
    __syncthreads();

    const int w = tid >> 6;
    const int lane = tid & 63;
    for (int rr = w * 8; rr < w * 8 + 8; ++rr) {
        int c = cnt[rr];
        float inv = 1.0f / ((float)c + 1e-8f);
        int cc = (c < CAP) ? c : CAP;
        float ax = 0.f, ay = 0.f, az = 0.f, aw = 0.f;
        for (int i = 0; i < cc; ++i) {
            const float4* ip = (const float4*)(incoming + ((long)b * NN + lst[rr][i]) * DD);
            float4 v = ip[lane];
            ax += v.x; ay += v.y; az += v.z; aw += v.w;
        }
        const float4* self4 = (const float4*)(incoming + ((long)b * NN + n0 + rr) * DD);
        float4 sv = self4[lane];
        float4 o;
        o.x = 0.8f * sv.x + 0.2f * inv * ax;
        o.y = 0.8f * sv.y + 0.2f * inv * ay;
        o.z = 0.8f * sv.z + 0.2f * inv * az;
        o.w = 0.8f * sv.w + 0.2f * inv * aw;
        ((float4*)(outs + ((long)b * NN + n0 + rr) * DD))[lane] = o;
    }
}

// ---------------------------------------------------------------------------
// K4: hdc = tanh(3(out@Wh+bh)); bind; decay-write; cosine read.
// Ss reads are wave-uniform float4 broadcasts; Wt reads stride-1 scalar.
// ---------------------------------------------------------------------------
__global__ __launch_bounds__(256) void k_mem(
    const float* __restrict__ outs, const float* __restrict__ Wh,
    const float* __restrict__ bh, const float* __restrict__ keys,
    const float* __restrict__ pos_codes, const int* __restrict__ stepp,
    const float* __restrict__ mem,
    float* __restrict__ epi_out, float* __restrict__ sim_out)
{
    __shared__ float Ss[16][DD];    // 16KB
    __shared__ float Wt[8][HH];     // 32KB
    __shared__ float red[4][8][3];

    const int tid = threadIdx.x;
    const long row0 = (long)blockIdx.x * 16;

    {
        const float4* g4 = (const float4*)(outs + row0 * DD);
        float4* s4 = (float4*)(&Ss[0][0]);
#pragma unroll
        for (int i = 0; i < 4; ++i) s4[tid + i * 256] = g4[tid + i * 256];
    }

    const int hg = tid & 127;       // h = hg + 128k
    const int rg = tid >> 7;        // rows rg*8+j
    float acc[8][8];
#pragma unroll
    for (int j = 0; j < 8; ++j)
#pragma unroll
        for (int k = 0; k < 8; ++k) acc[j][k] = 0.f;

    for (int dt = 0; dt < DD / 8; ++dt) {
        __syncthreads();
        {
            const float4* g4 = (const float4*)(Wh + (long)dt * 8 * HH);
            float4* s4 = (float4*)(&Wt[0][0]);
#pragma unroll
            for (int t = 0; t < 8; ++t) s4[tid + t * 256] = g4[tid + t * 256];
        }
        __syncthreads();
#pragma unroll
        for (int dq = 0; dq < 2; ++dq) {
            float sv[8][4];
#pragma unroll
            for (int j = 0; j < 8; ++j) {
                float4 t4 = *(const float4*)(&Ss[rg * 8 + j][dt * 8 + dq * 4]);
                sv[j][0] = t4.x; sv[j][1] = t4.y; sv[j][2] = t4.z; sv[j][3] = t4.w;
            }
#pragma unroll
            for (int d2 = 0; d2 < 4; ++d2) {
                float wvv[8];
#pragma unroll
                for (int k = 0; k < 8; ++k) wvv[k] = Wt[dq * 4 + d2][hg + 128 * k];
#pragma unroll
                for (int j = 0; j < 8; ++j)
#pragma unroll
                    for (int k = 0; k < 8; ++k)
                        acc[j][k] = fmaf(sv[j][d2], wvv[k], acc[j][k]);
            }
        }
    }

    const int step = stepp[0];
    const int prow = ((step % NCC) + NCC) % NCC;
    float dnp[8], dnn[8], dpp[8];
#pragma unroll
    for (int j = 0; j < 8; ++j) { dnp[j] = 0.f; dnn[j] = 0.f; dpp[j] = 0.f; }

#pragma unroll
    for (int k = 0; k < 8; ++k) {
        int h = hg + 128 * k;
        float ps = pos_codes[(long)prow * HH + h];
        float bb = bh[h];
#pragma unroll
        for (int j = 0; j < 8; ++j) {
            long row = row0 + rg * 8 + j;
            int n = (int)(row & (NN - 1));
            float y = acc[j][k] + bb;
            float hd = tanhf(3.0f * y);
            float per = hd * keys[(long)n * HH + h];
            float bound = per * ps;
            float ne = 0.95f * mem[row * HH + h] + 0.05f * bound;
            epi_out[row * HH + h] = ne;
            dnp[j] = fmaf(ne, per, dnp[j]);
            dnn[j] = fmaf(ne, ne, dnn[j]);
            dpp[j] = fmaf(per, per, dpp[j]);
        }
    }

#pragma unroll
    for (int j = 0; j < 8; ++j) {
#pragma unroll
        for (int off = 32; off >= 1; off >>= 1) {
            dnp[j] += __shfl_xor(dnp[j], off, 64);
            dnn[j] += __shfl_xor(dnn[j], off, 64);
            dpp[j] += __shfl_xor(dpp[j], off, 64);
        }
    }
    const int w = tid >> 6;
    const int lane = tid & 63;
    if (lane == 0) {
#pragma unroll
        for (int j = 0; j < 8; ++j) {
            red[w][j][0] = dnp[j]; red[w][j][1] = dnn[j]; red[w][j][2] = dpp[j];
        }
    }
    __syncthreads();
    if (tid < 16) {
        int rgp = tid >> 3, j = tid & 7;
        float dot = red[rgp * 2][j][0] + red[rgp * 2 + 1][j][0];
        float nn  = red[rgp * 2][j][1] + red[rgp * 2 + 1][j][1];
        float pp  = red[rgp * 2][j][2] + red[rgp * 2 + 1][j][2];
        float na = fmaxf(sqrtf(nn), 1e-8f);
        float nb = fmaxf(sqrtf(pp), 1e-8f);
        sim_out[row0 + rgp * 8 + j] = dot / (na * nb);
    }
}

// ---------------------------------------------------------------------------
extern "C" void kernel_launch(void* const* d_in, const int* in_sizes, int n_in,
                              void* d_out, int out_size, void* d_ws, size_t ws_size,
                              hipStream_t stream)
{
    const float* states  = (const float*)d_in[0];
    const float* actions = (const float*)d_in[1];
    const float* mem     = (const float*)d_in[2];
    const float* Wq = (const float*)d_in[3];
    const float* bq = (const float*)d_in[4];
    const float* Wk = (const float*)d_in[5];
    const float* bk = (const float*)d_in[6];
    const float* Wc = (const float*)d_in[7];
    const float* bc = (const float*)d_in[8];
    const float* Wh = (const float*)d_in[9];
    const float* bh = (const float*)d_in[10];
    const float* keys = (const float*)d_in[11];
    const float* pos  = (const float*)d_in[12];
    const int*   step = (const int*)d_in[13];

    float* ws = (float*)d_ws;
    float* Q        = ws;                    // 1,048,576 floats
    float* K        = ws + 1048576;          // 1,048,576
    float* PN       = ws + 2097152;          // 1,048,576
    float* incoming = ws + 3145728;          // 4,194,304

    float* outs = (float*)d_out;                       // B*N*D
    float* epi  = outs + (long)BB * NN * DD;           // B*N*H
    float* simo = epi + (long)BB * NN * HH;            // B*N

    hipLaunchKernelGGL(k_proj, dim3(BB * NN / 16), dim3(256), 0, stream,
                       actions, Wq, bq, Wk, bk, Wc, bc, Q, K, PN);
    hipLaunchKernelGGL(k_topk, dim3(BB * (NN / 32)), dim3(256), 0, stream,
                       Q, K, states, incoming);
    hipLaunchKernelGGL(k_coal, dim3(BB * (NN / 32)), dim3(256), 0, stream,
                       PN, incoming, outs);
    hipLaunchKernelGGL(k_mem, dim3(BB * NN / 16), dim3(256), 0, stream,
                       outs, Wh, bh, keys, pos, step, mem, epi, simo);
}

// Round 3
// 703.490 us; speedup vs baseline: 1.0955x; 1.0955x over previous
//
#include <hip/hip_runtime.h>

#define BB 4
#define NN 4096
#define DD 256
#define PP 64
#define HH 1024
#define NCC 256
#define TOPK 8

// ---------------------------------------------------------------------------
// K1: Q = A@Wq+bq, K = A@Wk+bk, proj = A@Wc+bc, pn = proj/max(||proj||,1e-12)
// ---------------------------------------------------------------------------
__global__ __launch_bounds__(256) void k_proj(
    const float* __restrict__ act,
    const float* __restrict__ Wq, const float* __restrict__ bq,
    const float* __restrict__ Wk, const float* __restrict__ bk,
    const float* __restrict__ Wc, const float* __restrict__ bc,
    float* __restrict__ Qo, float* __restrict__ Ko, float* __restrict__ PNo)
{
    __shared__ float As[16][DD];   // 16KB
    __shared__ float Ps[16][PP];   // 4KB
    const int tid = threadIdx.x;
    const long row0 = (long)blockIdx.x * 16;

    {
        const float4* g4 = (const float4*)(act + row0 * DD);
        float4* s4 = (float4*)(&As[0][0]);
#pragma unroll
        for (int i = 0; i < 4; ++i) s4[tid + i * 256] = g4[tid + i * 256];
    }
    __syncthreads();

    const int col = tid & 63;
    const int rg  = tid >> 6;   // 0..3 -> rows rg*4+j
    float aq[4], ak[4], ac[4];
#pragma unroll
    for (int j = 0; j < 4; ++j) { aq[j] = bq[col]; ak[j] = bk[col]; ac[j] = bc[col]; }

    for (int d = 0; d < DD; ++d) {
        float wq = Wq[d * PP + col];
        float wk = Wk[d * PP + col];
        float wc = Wc[d * PP + col];
#pragma unroll
        for (int j = 0; j < 4; ++j) {
            float a = As[rg * 4 + j][d];
            aq[j] = fmaf(a, wq, aq[j]);
            ak[j] = fmaf(a, wk, ak[j]);
            ac[j] = fmaf(a, wc, ac[j]);
        }
    }
#pragma unroll
    for (int j = 0; j < 4; ++j) {
        long r = row0 + rg * 4 + j;
        Qo[r * PP + col] = aq[j];
        Ko[r * PP + col] = ak[j];
        Ps[rg * 4 + j][col] = ac[j];
    }
    __syncthreads();

    const int w = tid >> 6;
    const int lane = tid & 63;
#pragma unroll
    for (int j = 0; j < 4; ++j) {
        int r = w * 4 + j;
        float v = Ps[r][lane];
        float ss = v * v;
#pragma unroll
        for (int off = 32; off >= 1; off >>= 1) ss += __shfl_xor(ss, off, 64);
        float nrm = fmaxf(sqrtf(ss), 1e-12f);
        PNo[(row0 + r) * PP + lane] = v / nrm;
    }
}

// ---------------------------------------------------------------------------
// K2: scores = Q K^T / 8 -> per-row top-8 -> softmax -> incoming gather.
// K tile: XOR-swizzled float4 slots (slot ^ (row&15)), row stride 64 dwords.
// 32 read-rows cover all 32 banks at the 512B/wave BW floor.
// ---------------------------------------------------------------------------
__global__ __launch_bounds__(256) void k_topk(
    const float* __restrict__ Q, const float* __restrict__ K,
    const float* __restrict__ states, float* __restrict__ incoming)
{
    __shared__ float Qs[32][PP];                    // 8KB
    __shared__ union UU {
        float4 Ks4[128 * 16];                       // 32KB, swizzled
        struct MM { float cv[32][256]; unsigned short ci[32][256]; } m;  // 48KB
    } u;

    const int tid = threadIdx.x;
    const int b  = blockIdx.x >> 7;
    const int n0 = (blockIdx.x & 127) << 5;

    {
        const float4* g4 = (const float4*)(Q + ((long)b * NN + n0) * PP);
        float4* s4 = (float4*)(&Qs[0][0]);
        s4[tid] = g4[tid];
        s4[tid + 256] = g4[tid + 256];
    }

    const int mg = tid & 31;        // m sub-index
    const int rg = tid >> 5;        // 0..7 -> rows rg+8j
    const int m15 = mg & 15;
    float topv[4][TOPK];
    int   topi[4][TOPK];
    float vmin[4];
#pragma unroll
    for (int j = 0; j < 4; ++j) {
        vmin[j] = -1e30f;
#pragma unroll
        for (int t = 0; t < TOPK; ++t) { topv[j][t] = -1e30f; topi[j][t] = 0; }
    }

    for (int mt = 0; mt < NN / 128; ++mt) {
        const int m0 = mt << 7;
        __syncthreads();
        {
            const float4* g4 = (const float4*)(K + ((long)b * NN + m0) * PP);
#pragma unroll
            for (int t = 0; t < 8; ++t) {
                int q = tid + t * 256;                 // 0..2047 float4s
                int row = q >> 4, sl = q & 15;
                u.Ks4[(row << 4) | (sl ^ (row & 15))] = g4[q];
            }
        }
        __syncthreads();

        float s[4][4];
#pragma unroll
        for (int j = 0; j < 4; ++j)
#pragma unroll
            for (int k = 0; k < 4; ++k) s[j][k] = 0.f;

#pragma unroll 4
        for (int sl = 0; sl < 16; ++sl) {              // p = 4*sl
            const int sw = sl ^ m15;
            float4 qv[4], kv[4];
#pragma unroll
            for (int j = 0; j < 4; ++j) qv[j] = *(const float4*)(&Qs[rg + 8 * j][sl << 2]);
#pragma unroll
            for (int k = 0; k < 4; ++k) kv[k] = u.Ks4[((mg + 32 * k) << 4) + sw];
#pragma unroll
            for (int j = 0; j < 4; ++j)
#pragma unroll
                for (int k = 0; k < 4; ++k) {
                    s[j][k] = fmaf(qv[j].x, kv[k].x, s[j][k]);
                    s[j][k] = fmaf(qv[j].y, kv[k].y, s[j][k]);
                    s[j][k] = fmaf(qv[j].z, kv[k].z, s[j][k]);
                    s[j][k] = fmaf(qv[j].w, kv[k].w, s[j][k]);
                }
        }

#pragma unroll
        for (int j = 0; j < 4; ++j) {
#pragma unroll
            for (int k = 0; k < 4; ++k) {
                float val = s[j][k] * 0.125f;
                int idx = m0 + mg + 32 * k;
                if (val > vmin[j]) {
                    float mv = topv[j][0];
#pragma unroll
                    for (int t = 1; t < TOPK; ++t) mv = fminf(mv, topv[j][t]);
                    bool done = false;
#pragma unroll
                    for (int t = 0; t < TOPK; ++t) {   // static-index replace
                        bool take = (!done) && (topv[j][t] == mv);
                        if (take) { topv[j][t] = val; topi[j][t] = idx; done = true; }
                    }
                    float nm = topv[j][0];
#pragma unroll
                    for (int t = 1; t < TOPK; ++t) nm = fminf(nm, topv[j][t]);
                    vmin[j] = nm;
                }
            }
        }
    }
    __syncthreads();

    // dump per-thread candidates: row rr gets 32 threads x 8 = 256 candidates
#pragma unroll
    for (int j = 0; j < 4; ++j) {
        int rr = rg + 8 * j;
#pragma unroll
        for (int t = 0; t < TOPK; ++t) {
            u.m.cv[rr][mg * 8 + t] = topv[j][t];
            u.m.ci[rr][mg * 8 + t] = (unsigned short)topi[j][t];
        }
    }
    __syncthreads();

    // merge: wave w handles rows w*8 .. w*8+7
    const int w = tid >> 6;
    const int lane = tid & 63;
    for (int rr = w * 8; rr < w * 8 + 8; ++rr) {
        float v0 = u.m.cv[rr][lane];
        float v1 = u.m.cv[rr][lane + 64];
        float v2 = u.m.cv[rr][lane + 128];
        float v3 = u.m.cv[rr][lane + 192];
        float wv[8]; int wi[8];
#pragma unroll
        for (int e = 0; e < TOPK; ++e) {
            float lv = v0; int ls = 0;
            if (v1 > lv) { lv = v1; ls = 1; }
            if (v2 > lv) { lv = v2; ls = 2; }
            if (v3 > lv) { lv = v3; ls = 3; }
            int slot = ls * 64 + lane;
#pragma unroll
            for (int off = 32; off >= 1; off >>= 1) {
                float ov = __shfl_xor(lv, off, 64);
                int   os = __shfl_xor(slot, off, 64);
                if (ov > lv || (ov == lv && os < slot)) { lv = ov; slot = os; }
            }
            wv[e] = lv;
            wi[e] = (int)u.m.ci[rr][slot];
            if (slot == 0 * 64 + lane) v0 = -1e30f;
            if (slot == 1 * 64 + lane) v1 = -1e30f;
            if (slot == 2 * 64 + lane) v2 = -1e30f;
            if (slot == 3 * 64 + lane) v3 = -1e30f;
        }
        float mx = wv[0];
        float ex[8]; float Z = 0.f;
#pragma unroll
        for (int e = 0; e < TOPK; ++e) { ex[e] = expf(wv[e] - mx); Z += ex[e]; }
        float invZ = 1.0f / Z;

        float ax = 0.f, ay = 0.f, az = 0.f, aw = 0.f;
#pragma unroll
        for (int e = 0; e < TOPK; ++e) {
            const float4* sp = (const float4*)(states + ((long)b * NN + wi[e]) * DD);
            float4 sv = sp[lane];
            float we = ex[e] * invZ;
            ax = fmaf(we, sv.x, ax); ay = fmaf(we, sv.y, ay);
            az = fmaf(we, sv.z, az); aw = fmaf(we, sv.w, aw);
        }
        float4 o; o.x = ax; o.y = ay; o.z = az; o.w = aw;
        ((float4*)(incoming + ((long)b * NN + n0 + rr) * DD))[lane] = o;
    }
}

// ---------------------------------------------------------------------------
// K3: sim = pn pn^T; cmask = sim>0.7; combined; out = 0.8*inc + 0.2*combined
// Same swizzled K-tile. ~44KB LDS -> 3 blocks/CU.
// ---------------------------------------------------------------------------
#define CAP 64
__global__ __launch_bounds__(256) void k_coal(
    const float* __restrict__ PN, const float* __restrict__ incoming,
    float* __restrict__ outs)
{
    __shared__ float Qs[32][PP];        // 8KB
    __shared__ float4 Ks4[128 * 16];    // 32KB, swizzled
    __shared__ int cnt[32];
    __shared__ unsigned short lst[32][CAP];   // 4KB

    const int tid = threadIdx.x;
    const int b  = blockIdx.x >> 7;
    const int n0 = (blockIdx.x & 127) << 5;

    if (tid < 32) cnt[tid] = 0;
    {
        const float4* g4 = (const float4*)(PN + ((long)b * NN + n0) * PP);
        float4* s4 = (float4*)(&Qs[0][0]);
        s4[tid] = g4[tid];
        s4[tid + 256] = g4[tid + 256];
    }

    const int mg = tid & 31;
    const int rg = tid >> 5;
    const int m15 = mg & 15;

    for (int mt = 0; mt < NN / 128; ++mt) {
        const int m0 = mt << 7;
        __syncthreads();
        {
            const float4* g4 = (const float4*)(PN + ((long)b * NN + m0) * PP);
#pragma unroll
            for (int t = 0; t < 8; ++t) {
                int q = tid + t * 256;
                int row = q >> 4, sl = q & 15;
                Ks4[(row << 4) | (sl ^ (row & 15))] = g4[q];
            }
        }
        __syncthreads();

        float s[4][4];
#pragma unroll
        for (int j = 0; j < 4; ++j)
#pragma unroll
            for (int k = 0; k < 4; ++k) s[j][k] = 0.f;

#pragma unroll 4
        for (int sl = 0; sl < 16; ++sl) {
            const int sw = sl ^ m15;
            float4 qv[4], kv[4];
#pragma unroll
            for (int j = 0; j < 4; ++j) qv[j] = *(const float4*)(&Qs[rg + 8 * j][sl << 2]);
#pragma unroll
            for (int k = 0; k < 4; ++k) kv[k] = Ks4[((mg + 32 * k) << 4) + sw];
#pragma unroll
            for (int j = 0; j < 4; ++j)
#pragma unroll
                for (int k = 0; k < 4; ++k) {
                    s[j][k] = fmaf(qv[j].x, kv[k].x, s[j][k]);
                    s[j][k] = fmaf(qv[j].y, kv[k].y, s[j][k]);
                    s[j][k] = fmaf(qv[j].z, kv[k].z, s[j][k]);
                    s[j][k] = fmaf(qv[j].w, kv[k].w, s[j][k]);
                }
        }

#pragma unroll
        for (int j = 0; j < 4; ++j)
#pragma unroll
            for (int k = 0; k < 4; ++k) {
                if (s[j][k] > 0.7f) {
                    int pos = atomicAdd(&cnt[rg + 8 * j], 1);
                    if (pos < CAP) lst[rg + 8 * j][pos] = (unsigned short)(m0 + mg + 32 * k);
                }
            }
    }
    __syncthreads();

    const int w = tid >> 6;
    const int lane = tid & 63;
    for (int rr = w * 8; rr < w * 8 + 8; ++rr) {
        int c = cnt[rr];
        float inv = 1.0f / ((float)c + 1e-8f);
        int cc = (c < CAP) ? c : CAP;
        float ax = 0.f, ay = 0.f, az = 0.f, aw = 0.f;
        for (int i = 0; i < cc; ++i) {
            const float4* ip = (const float4*)(incoming + ((long)b * NN + lst[rr][i]) * DD);
            float4 v = ip[lane];
            ax += v.x; ay += v.y; az += v.z; aw += v.w;
        }
        const float4* self4 = (const float4*)(incoming + ((long)b * NN + n0 + rr) * DD);
        float4 sv = self4[lane];
        float4 o;
        o.x = 0.8f * sv.x + 0.2f * inv * ax;
        o.y = 0.8f * sv.y + 0.2f * inv * ay;
        o.z = 0.8f * sv.z + 0.2f * inv * az;
        o.w = 0.8f * sv.w + 0.2f * inv * aw;
        ((float4*)(outs + ((long)b * NN + n0 + rr) * DD))[lane] = o;
    }
}

// ---------------------------------------------------------------------------
// K4: hdc = tanh(3(out@Wh+bh)); bind; decay-write; cosine read.
// ---------------------------------------------------------------------------
__global__ __launch_bounds__(256) void k_mem(
    const float* __restrict__ outs, const float* __restrict__ Wh,
    const float* __restrict__ bh, const float* __restrict__ keys,
    const float* __restrict__ pos_codes, const int* __restrict__ stepp,
    const float* __restrict__ mem,
    float* __restrict__ epi_out, float* __restrict__ sim_out)
{
    __shared__ float Ss[16][DD];    // 16KB
    __shared__ float Wt[8][HH];     // 32KB
    __shared__ float red[4][8][3];

    const int tid = threadIdx.x;
    const long row0 = (long)blockIdx.x * 16;

    {
        const float4* g4 = (const float4*)(outs + row0 * DD);
        float4* s4 = (float4*)(&Ss[0][0]);
#pragma unroll
        for (int i = 0; i < 4; ++i) s4[tid + i * 256] = g4[tid + i * 256];
    }

    const int hg = tid & 127;       // h = hg + 128k
    const int rg = tid >> 7;        // rows rg*8+j
    float acc[8][8];
#pragma unroll
    for (int j = 0; j < 8; ++j)
#pragma unroll
        for (int k = 0; k < 8; ++k) acc[j][k] = 0.f;

    for (int dt = 0; dt < DD / 8; ++dt) {
        __syncthreads();
        {
            const float4* g4 = (const float4*)(Wh + (long)dt * 8 * HH);
            float4* s4 = (float4*)(&Wt[0][0]);
#pragma unroll
            for (int t = 0; t < 8; ++t) s4[tid + t * 256] = g4[tid + t * 256];
        }
        __syncthreads();
#pragma unroll
        for (int dq = 0; dq < 2; ++dq) {
            float sv[8][4];
#pragma unroll
            for (int j = 0; j < 8; ++j) {
                float4 t4 = *(const float4*)(&Ss[rg * 8 + j][dt * 8 + dq * 4]);
                sv[j][0] = t4.x; sv[j][1] = t4.y; sv[j][2] = t4.z; sv[j][3] = t4.w;
            }
#pragma unroll
            for (int d2 = 0; d2 < 4; ++d2) {
                float wvv[8];
#pragma unroll
                for (int k = 0; k < 8; ++k) wvv[k] = Wt[dq * 4 + d2][hg + 128 * k];
#pragma unroll
                for (int j = 0; j < 8; ++j)
#pragma unroll
                    for (int k = 0; k < 8; ++k)
                        acc[j][k] = fmaf(sv[j][d2], wvv[k], acc[j][k]);
            }
        }
    }

    const int step = stepp[0];
    const int prow = ((step % NCC) + NCC) % NCC;
    float dnp[8], dnn[8], dpp[8];
#pragma unroll
    for (int j = 0; j < 8; ++j) { dnp[j] = 0.f; dnn[j] = 0.f; dpp[j] = 0.f; }

#pragma unroll
    for (int k = 0; k < 8; ++k) {
        int h = hg + 128 * k;
        float ps = pos_codes[(long)prow * HH + h];
        float bb = bh[h];
#pragma unroll
        for (int j = 0; j < 8; ++j) {
            long row = row0 + rg * 8 + j;
            int n = (int)(row & (NN - 1));
            float y = acc[j][k] + bb;
            float hd = tanhf(3.0f * y);
            float per = hd * keys[(long)n * HH + h];
            float bound = per * ps;
            float ne = 0.95f * mem[row * HH + h] + 0.05f * bound;
            epi_out[row * HH + h] = ne;
            dnp[j] = fmaf(ne, per, dnp[j]);
            dnn[j] = fmaf(ne, ne, dnn[j]);
            dpp[j] = fmaf(per, per, dpp[j]);
        }
    }

#pragma unroll
    for (int j = 0; j < 8; ++j) {
#pragma unroll
        for (int off = 32; off >= 1; off >>= 1) {
            dnp[j] += __shfl_xor(dnp[j], off, 64);
            dnn[j] += __shfl_xor(dnn[j], off, 64);
            dpp[j] += __shfl_xor(dpp[j], off, 64);
        }
    }
    const int w = tid >> 6;
    const int lane = tid & 63;
    if (lane == 0) {
#pragma unroll
        for (int j = 0; j < 8; ++j) {
            red[w][j][0] = dnp[j]; red[w][j][1] = dnn[j]; red[w][j][2] = dpp[j];
        }
    }
    __syncthreads();
    if (tid < 16) {
        int rgp = tid >> 3, j = tid & 7;
        float dot = red[rgp * 2][j][0] + red[rgp * 2 + 1][j][0];
        float nn  = red[rgp * 2][j][1] + red[rgp * 2 + 1][j][1];
        float pp  = red[rgp * 2][j][2] + red[rgp * 2 + 1][j][2];
        float na = fmaxf(sqrtf(nn), 1e-8f);
        float nb = fmaxf(sqrtf(pp), 1e-8f);
        sim_out[row0 + rgp * 8 + j] = dot / (na * nb);
    }
}

// ---------------------------------------------------------------------------
extern "C" void kernel_launch(void* const* d_in, const int* in_sizes, int n_in,
                              void* d_out, int out_size, void* d_ws, size_t ws_size,
                              hipStream_t stream)
{
    const float* states  = (const float*)d_in[0];
    const float* actions = (const float*)d_in[1];
    const float* mem     = (const float*)d_in[2];
    const float* Wq = (const float*)d_in[3];
    const float* bq = (const float*)d_in[4];
    const float* Wk = (const float*)d_in[5];
    const float* bk = (const float*)d_in[6];
    const float* Wc = (const float*)d_in[7];
    const float* bc = (const float*)d_in[8];
    const float* Wh = (const float*)d_in[9];
    const float* bh = (const float*)d_in[10];
    const float* keys = (const float*)d_in[11];
    const float* pos  = (const float*)d_in[12];
    const int*   step = (const int*)d_in[13];

    float* ws = (float*)d_ws;
    float* Q        = ws;                    // 1,048,576 floats
    float* K        = ws + 1048576;          // 1,048,576
    float* PN       = ws + 2097152;          // 1,048,576
    float* incoming = ws + 3145728;          // 4,194,304

    float* outs = (float*)d_out;                       // B*N*D
    float* epi  = outs + (long)BB * NN * DD;           // B*N*H
    float* simo = epi + (long)BB * NN * HH;            // B*N

    hipLaunchKernelGGL(k_proj, dim3(BB * NN / 16), dim3(256), 0, stream,
                       actions, Wq, bq, Wk, bk, Wc, bc, Q, K, PN);
    hipLaunchKernelGGL(k_topk, dim3(BB * (NN / 32)), dim3(256), 0, stream,
                       Q, K, states, incoming);
    hipLaunchKernelGGL(k_coal, dim3(BB * (NN / 32)), dim3(256), 0, stream,
                       PN, incoming, outs);
    hipLaunchKernelGGL(k_mem, dim3(BB * NN / 16), dim3(256), 0, stream,
                       outs, Wh, bh, keys, pos, step, mem, epi, simo);
}

// Round 4
// 695.640 us; speedup vs baseline: 1.1079x; 1.0113x over previous
//
#include <hip/hip_runtime.h>

#define BB 4
#define NN 4096
#define DD 256
#define PP 64
#define HH 1024
#define NCC 256
#define TOPK 8

// ---------------------------------------------------------------------------
// K1: Q = A@Wq+bq, K = A@Wk+bk, proj = A@Wc+bc, pn = proj/max(||proj||,1e-12)
// ---------------------------------------------------------------------------
__global__ __launch_bounds__(256) void k_proj(
    const float* __restrict__ act,
    const float* __restrict__ Wq, const float* __restrict__ bq,
    const float* __restrict__ Wk, const float* __restrict__ bk,
    const float* __restrict__ Wc, const float* __restrict__ bc,
    float* __restrict__ Qo, float* __restrict__ Ko, float* __restrict__ PNo)
{
    __shared__ float As[16][DD];   // 16KB
    __shared__ float Ps[16][PP];   // 4KB
    const int tid = threadIdx.x;
    const long row0 = (long)blockIdx.x * 16;

    {
        const float4* g4 = (const float4*)(act + row0 * DD);
        float4* s4 = (float4*)(&As[0][0]);
#pragma unroll
        for (int i = 0; i < 4; ++i) s4[tid + i * 256] = g4[tid + i * 256];
    }
    __syncthreads();

    const int col = tid & 63;
    const int rg  = tid >> 6;   // 0..3 -> rows rg*4+j
    float aq[4], ak[4], ac[4];
#pragma unroll
    for (int j = 0; j < 4; ++j) { aq[j] = bq[col]; ak[j] = bk[col]; ac[j] = bc[col]; }

    for (int d = 0; d < DD; ++d) {
        float wq = Wq[d * PP + col];
        float wk = Wk[d * PP + col];
        float wc = Wc[d * PP + col];
#pragma unroll
        for (int j = 0; j < 4; ++j) {
            float a = As[rg * 4 + j][d];
            aq[j] = fmaf(a, wq, aq[j]);
            ak[j] = fmaf(a, wk, ak[j]);
            ac[j] = fmaf(a, wc, ac[j]);
        }
    }
#pragma unroll
    for (int j = 0; j < 4; ++j) {
        long r = row0 + rg * 4 + j;
        Qo[r * PP + col] = aq[j];
        Ko[r * PP + col] = ak[j];
        Ps[rg * 4 + j][col] = ac[j];
    }
    __syncthreads();

    const int w = tid >> 6;
    const int lane = tid & 63;
#pragma unroll
    for (int j = 0; j < 4; ++j) {
        int r = w * 4 + j;
        float v = Ps[r][lane];
        float ss = v * v;
#pragma unroll
        for (int off = 32; off >= 1; off >>= 1) ss += __shfl_xor(ss, off, 64);
        float nrm = fmaxf(sqrtf(ss), 1e-12f);
        PNo[(row0 + r) * PP + lane] = v / nrm;
    }
}

// ---------------------------------------------------------------------------
// K2: scores = Q K^T -> per-row top-8 (raw scores; /8 applied at softmax).
// K tile: XOR-swizzled float4 slots (slot ^ (row&15)), row stride 64 dwords.
// __launch_bounds__(256,2): LDS caps us at 2 blocks/CU anyway; allow up to
// 256 VGPR so topv/topi/s/qv/kv (~125 live) don't spill to scratch.
// ---------------------------------------------------------------------------
__global__ __launch_bounds__(256, 2) void k_topk(
    const float* __restrict__ Q, const float* __restrict__ K,
    const float* __restrict__ states, float* __restrict__ incoming)
{
    __shared__ float Qs[32][PP];                    // 8KB
    __shared__ union UU {
        float4 Ks4[128 * 16];                       // 32KB, swizzled
        struct MM { float cv[32][256]; unsigned short ci[32][256]; } m;  // 48KB
    } u;

    const int tid = threadIdx.x;
    const int b  = blockIdx.x >> 7;
    const int n0 = (blockIdx.x & 127) << 5;

    {
        const float4* g4 = (const float4*)(Q + ((long)b * NN + n0) * PP);
        float4* s4 = (float4*)(&Qs[0][0]);
        s4[tid] = g4[tid];
        s4[tid + 256] = g4[tid + 256];
    }

    const int mg = tid & 31;        // m sub-index
    const int rg = tid >> 5;        // 0..7 -> rows rg+8j
    const int m15 = mg & 15;
    float topv[4][TOPK];
    int   topi[4][TOPK];
    float vmin[4];
#pragma unroll
    for (int j = 0; j < 4; ++j) {
        vmin[j] = -1e30f;
#pragma unroll
        for (int t = 0; t < TOPK; ++t) { topv[j][t] = -1e30f; topi[j][t] = 0; }
    }

    for (int mt = 0; mt < NN / 128; ++mt) {
        const int m0 = mt << 7;
        __syncthreads();
        {
            const float4* g4 = (const float4*)(K + ((long)b * NN + m0) * PP);
#pragma unroll
            for (int t = 0; t < 8; ++t) {
                int q = tid + t * 256;                 // 0..2047 float4s
                int row = q >> 4, sl = q & 15;
                u.Ks4[(row << 4) | (sl ^ (row & 15))] = g4[q];
            }
        }
        __syncthreads();

        float s[4][4];
#pragma unroll
        for (int j = 0; j < 4; ++j)
#pragma unroll
            for (int k = 0; k < 4; ++k) s[j][k] = 0.f;

#pragma unroll 4
        for (int sl = 0; sl < 16; ++sl) {              // p = 4*sl
            const int sw = sl ^ m15;
            float4 qv[4], kv[4];
#pragma unroll
            for (int j = 0; j < 4; ++j) qv[j] = *(const float4*)(&Qs[rg + 8 * j][sl << 2]);
#pragma unroll
            for (int k = 0; k < 4; ++k) kv[k] = u.Ks4[((mg + 32 * k) << 4) + sw];
#pragma unroll
            for (int j = 0; j < 4; ++j)
#pragma unroll
                for (int k = 0; k < 4; ++k) {
                    s[j][k] = fmaf(qv[j].x, kv[k].x, s[j][k]);
                    s[j][k] = fmaf(qv[j].y, kv[k].y, s[j][k]);
                    s[j][k] = fmaf(qv[j].z, kv[k].z, s[j][k]);
                    s[j][k] = fmaf(qv[j].w, kv[k].w, s[j][k]);
                }
        }

#pragma unroll
        for (int j = 0; j < 4; ++j) {
#pragma unroll
            for (int k = 0; k < 4; ++k) {
                float val = s[j][k];                   // raw score (scale-monotone)
                int idx = m0 + mg + 32 * k;
                if (val > vmin[j]) {
                    float mv = topv[j][0];
#pragma unroll
                    for (int t = 1; t < TOPK; ++t) mv = fminf(mv, topv[j][t]);
                    bool done = false;
#pragma unroll
                    for (int t = 0; t < TOPK; ++t) {   // static-index replace
                        bool take = (!done) && (topv[j][t] == mv);
                        if (take) { topv[j][t] = val; topi[j][t] = idx; done = true; }
                    }
                    float nm = topv[j][0];
#pragma unroll
                    for (int t = 1; t < TOPK; ++t) nm = fminf(nm, topv[j][t]);
                    vmin[j] = nm;
                }
            }
        }
    }
    __syncthreads();

    // dump per-thread candidates: row rr gets 32 threads x 8 = 256 candidates
#pragma unroll
    for (int j = 0; j < 4; ++j) {
        int rr = rg + 8 * j;
#pragma unroll
        for (int t = 0; t < TOPK; ++t) {
            u.m.cv[rr][mg * 8 + t] = topv[j][t];
            u.m.ci[rr][mg * 8 + t] = (unsigned short)topi[j][t];
        }
    }
    __syncthreads();

    // merge: wave w handles rows w*8 .. w*8+7
    const int w = tid >> 6;
    const int lane = tid & 63;
    for (int rr = w * 8; rr < w * 8 + 8; ++rr) {
        float v0 = u.m.cv[rr][lane];
        float v1 = u.m.cv[rr][lane + 64];
        float v2 = u.m.cv[rr][lane + 128];
        float v3 = u.m.cv[rr][lane + 192];
        float wv[8]; int wi[8];
#pragma unroll
        for (int e = 0; e < TOPK; ++e) {
            float lv = v0; int ls = 0;
            if (v1 > lv) { lv = v1; ls = 1; }
            if (v2 > lv) { lv = v2; ls = 2; }
            if (v3 > lv) { lv = v3; ls = 3; }
            int slot = ls * 64 + lane;
#pragma unroll
            for (int off = 32; off >= 1; off >>= 1) {
                float ov = __shfl_xor(lv, off, 64);
                int   os = __shfl_xor(slot, off, 64);
                if (ov > lv || (ov == lv && os < slot)) { lv = ov; slot = os; }
            }
            wv[e] = lv;
            wi[e] = (int)u.m.ci[rr][slot];
            if (slot == 0 * 64 + lane) v0 = -1e30f;
            if (slot == 1 * 64 + lane) v1 = -1e30f;
            if (slot == 2 * 64 + lane) v2 = -1e30f;
            if (slot == 3 * 64 + lane) v3 = -1e30f;
        }
        float mx = wv[0] * 0.125f;
        float ex[8]; float Z = 0.f;
#pragma unroll
        for (int e = 0; e < TOPK; ++e) { ex[e] = expf(wv[e] * 0.125f - mx); Z += ex[e]; }
        float invZ = 1.0f / Z;

        float ax = 0.f, ay = 0.f, az = 0.f, aw = 0.f;
#pragma unroll
        for (int e = 0; e < TOPK; ++e) {
            const float4* sp = (const float4*)(states + ((long)b * NN + wi[e]) * DD);
            float4 sv = sp[lane];
            float we = ex[e] * invZ;
            ax = fmaf(we, sv.x, ax); ay = fmaf(we, sv.y, ay);
            az = fmaf(we, sv.z, az); aw = fmaf(we, sv.w, aw);
        }
        float4 o; o.x = ax; o.y = ay; o.z = az; o.w = aw;
        ((float4*)(incoming + ((long)b * NN + n0 + rr) * DD))[lane] = o;
    }
}

// ---------------------------------------------------------------------------
// K3: sim = pn pn^T; cmask = sim>0.7; combined; out = 0.8*inc + 0.2*combined
// ---------------------------------------------------------------------------
#define CAP 64
__global__ __launch_bounds__(256, 2) void k_coal(
    const float* __restrict__ PN, const float* __restrict__ incoming,
    float* __restrict__ outs)
{
    __shared__ float Qs[32][PP];        // 8KB
    __shared__ float4 Ks4[128 * 16];    // 32KB, swizzled
    __shared__ int cnt[32];
    __shared__ unsigned short lst[32][CAP];   // 4KB

    const int tid = threadIdx.x;
    const int b  = blockIdx.x >> 7;
    const int n0 = (blockIdx.x & 127) << 5;

    if (tid < 32) cnt[tid] = 0;
    {
        const float4* g4 = (const float4*)(PN + ((long)b * NN + n0) * PP);
        float4* s4 = (float4*)(&Qs[0][0]);
        s4[tid] = g4[tid];
        s4[tid + 256] = g4[tid + 256];
    }

    const int mg = tid & 31;
    const int rg = tid >> 5;
    const int m15 = mg & 15;

    for (int mt = 0; mt < NN / 128; ++mt) {
        const int m0 = mt << 7;
        __syncthreads();
        {
            const float4* g4 = (const float4*)(PN + ((long)b * NN + m0) * PP);
#pragma unroll
            for (int t = 0; t < 8; ++t) {
                int q = tid + t * 256;
                int row = q >> 4, sl = q & 15;
                Ks4[(row << 4) | (sl ^ (row & 15))] = g4[q];
            }
        }
        __syncthreads();

        float s[4][4];
#pragma unroll
        for (int j = 0; j < 4; ++j)
#pragma unroll
            for (int k = 0; k < 4; ++k) s[j][k] = 0.f;

#pragma unroll 4
        for (int sl = 0; sl < 16; ++sl) {
            const int sw = sl ^ m15;
            float4 qv[4], kv[4];
#pragma unroll
            for (int j = 0; j < 4; ++j) qv[j] = *(const float4*)(&Qs[rg + 8 * j][sl << 2]);
#pragma unroll
            for (int k = 0; k < 4; ++k) kv[k] = Ks4[((mg + 32 * k) << 4) + sw];
#pragma unroll
            for (int j = 0; j < 4; ++j)
#pragma unroll
                for (int k = 0; k < 4; ++k) {
                    s[j][k] = fmaf(qv[j].x, kv[k].x, s[j][k]);
                    s[j][k] = fmaf(qv[j].y, kv[k].y, s[j][k]);
                    s[j][k] = fmaf(qv[j].z, kv[k].z, s[j][k]);
                    s[j][k] = fmaf(qv[j].w, kv[k].w, s[j][k]);
                }
        }

#pragma unroll
        for (int j = 0; j < 4; ++j)
#pragma unroll
            for (int k = 0; k < 4; ++k) {
                if (s[j][k] > 0.7f) {
                    int pos = atomicAdd(&cnt[rg + 8 * j], 1);
                    if (pos < CAP) lst[rg + 8 * j][pos] = (unsigned short)(m0 + mg + 32 * k);
                }
            }
    }
    __syncthreads();

    const int w = tid >> 6;
    const int lane = tid & 63;
    for (int rr = w * 8; rr < w * 8 + 8; ++rr) {
        int c = cnt[rr];
        float inv = 1.0f / ((float)c + 1e-8f);
        int cc = (c < CAP) ? c : CAP;
        float ax = 0.f, ay = 0.f, az = 0.f, aw = 0.f;
        for (int i = 0; i < cc; ++i) {
            const float4* ip = (const float4*)(incoming + ((long)b * NN + lst[rr][i]) * DD);
            float4 v = ip[lane];
            ax += v.x; ay += v.y; az += v.z; aw += v.w;
        }
        const float4* self4 = (const float4*)(incoming + ((long)b * NN + n0 + rr) * DD);
        float4 sv = self4[lane];
        float4 o;
        o.x = 0.8f * sv.x + 0.2f * inv * ax;
        o.y = 0.8f * sv.y + 0.2f * inv * ay;
        o.z = 0.8f * sv.z + 0.2f * inv * az;
        o.w = 0.8f * sv.w + 0.2f * inv * aw;
        ((float4*)(outs + ((long)b * NN + n0 + rr) * DD))[lane] = o;
    }
}

// ---------------------------------------------------------------------------
// K4: hdc = tanh(3(out@Wh+bh)); bind; decay-write; cosine read.
// ---------------------------------------------------------------------------
__global__ __launch_bounds__(256, 2) void k_mem(
    const float* __restrict__ outs, const float* __restrict__ Wh,
    const float* __restrict__ bh, const float* __restrict__ keys,
    const float* __restrict__ pos_codes, const int* __restrict__ stepp,
    const float* __restrict__ mem,
    float* __restrict__ epi_out, float* __restrict__ sim_out)
{
    __shared__ float Ss[16][DD];    // 16KB
    __shared__ float Wt[8][HH];     // 32KB
    __shared__ float red[4][8][3];

    const int tid = threadIdx.x;
    const long row0 = (long)blockIdx.x * 16;

    {
        const float4* g4 = (const float4*)(outs + row0 * DD);
        float4* s4 = (float4*)(&Ss[0][0]);
#pragma unroll
        for (int i = 0; i < 4; ++i) s4[tid + i * 256] = g4[tid + i * 256];
    }

    const int hg = tid & 127;       // h = hg + 128k
    const int rg = tid >> 7;        // rows rg*8+j
    float acc[8][8];
#pragma unroll
    for (int j = 0; j < 8; ++j)
#pragma unroll
        for (int k = 0; k < 8; ++k) acc[j][k] = 0.f;

    for (int dt = 0; dt < DD / 8; ++dt) {
        __syncthreads();
        {
            const float4* g4 = (const float4*)(Wh + (long)dt * 8 * HH);
            float4* s4 = (float4*)(&Wt[0][0]);
#pragma unroll
            for (int t = 0; t < 8; ++t) s4[tid + t * 256] = g4[tid + t * 256];
        }
        __syncthreads();
#pragma unroll
        for (int dq = 0; dq < 2; ++dq) {
            float sv[8][4];
#pragma unroll
            for (int j = 0; j < 8; ++j) {
                float4 t4 = *(const float4*)(&Ss[rg * 8 + j][dt * 8 + dq * 4]);
                sv[j][0] = t4.x; sv[j][1] = t4.y; sv[j][2] = t4.z; sv[j][3] = t4.w;
            }
#pragma unroll
            for (int d2 = 0; d2 < 4; ++d2) {
                float wvv[8];
#pragma unroll
                for (int k = 0; k < 8; ++k) wvv[k] = Wt[dq * 4 + d2][hg + 128 * k];
#pragma unroll
                for (int j = 0; j < 8; ++j)
#pragma unroll
                    for (int k = 0; k < 8; ++k)
                        acc[j][k] = fmaf(sv[j][d2], wvv[k], acc[j][k]);
            }
        }
    }

    const int step = stepp[0];
    const int prow = ((step % NCC) + NCC) % NCC;
    float dnp[8], dnn[8], dpp[8];
#pragma unroll
    for (int j = 0; j < 8; ++j) { dnp[j] = 0.f; dnn[j] = 0.f; dpp[j] = 0.f; }

#pragma unroll
    for (int k = 0; k < 8; ++k) {
        int h = hg + 128 * k;
        float ps = pos_codes[(long)prow * HH + h];
        float bb = bh[h];
#pragma unroll
        for (int j = 0; j < 8; ++j) {
            long row = row0 + rg * 8 + j;
            int n = (int)(row & (NN - 1));
            float y = acc[j][k] + bb;
            float hd = tanhf(3.0f * y);
            float per = hd * keys[(long)n * HH + h];
            float bound = per * ps;
            float ne = 0.95f * mem[row * HH + h] + 0.05f * bound;
            epi_out[row * HH + h] = ne;
            dnp[j] = fmaf(ne, per, dnp[j]);
            dnn[j] = fmaf(ne, ne, dnn[j]);
            dpp[j] = fmaf(per, per, dpp[j]);
        }
    }

#pragma unroll
    for (int j = 0; j < 8; ++j) {
#pragma unroll
        for (int off = 32; off >= 1; off >>= 1) {
            dnp[j] += __shfl_xor(dnp[j], off, 64);
            dnn[j] += __shfl_xor(dnn[j], off, 64);
            dpp[j] += __shfl_xor(dpp[j], off, 64);
        }
    }
    const int w = tid >> 6;
    const int lane = tid & 63;
    if (lane == 0) {
#pragma unroll
        for (int j = 0; j < 8; ++j) {
            red[w][j][0] = dnp[j]; red[w][j][1] = dnn[j]; red[w][j][2] = dpp[j];
        }
    }
    __syncthreads();
    if (tid < 16) {
        int rgp = tid >> 3, j = tid & 7;
        float dot = red[rgp * 2][j][0] + red[rgp * 2 + 1][j][0];
        float nn  = red[rgp * 2][j][1] + red[rgp * 2 + 1][j][1];
        float pp  = red[rgp * 2][j][2] + red[rgp * 2 + 1][j][2];
        float na = fmaxf(sqrtf(nn), 1e-8f);
        float nb = fmaxf(sqrtf(pp), 1e-8f);
        sim_out[row0 + rgp * 8 + j] = dot / (na * nb);
    }
}

// ---------------------------------------------------------------------------
extern "C" void kernel_launch(void* const* d_in, const int* in_sizes, int n_in,
                              void* d_out, int out_size, void* d_ws, size_t ws_size,
                              hipStream_t stream)
{
    const float* states  = (const float*)d_in[0];
    const float* actions = (const float*)d_in[1];
    const float* mem     = (const float*)d_in[2];
    const float* Wq = (const float*)d_in[3];
    const float* bq = (const float*)d_in[4];
    const float* Wk = (const float*)d_in[5];
    const float* bk = (const float*)d_in[6];
    const float* Wc = (const float*)d_in[7];
    const float* bc = (const float*)d_in[8];
    const float* Wh = (const float*)d_in[9];
    const float* bh = (const float*)d_in[10];
    const float* keys = (const float*)d_in[11];
    const float* pos  = (const float*)d_in[12];
    const int*   step = (const int*)d_in[13];

    float* ws = (float*)d_ws;
    float* Q        = ws;                    // 1,048,576 floats
    float* K        = ws + 1048576;          // 1,048,576
    float* PN       = ws + 2097152;          // 1,048,576
    float* incoming = ws + 3145728;          // 4,194,304

    float* outs = (float*)d_out;                       // B*N*D
    float* epi  = outs + (long)BB * NN * DD;           // B*N*H
    float* simo = epi + (long)BB * NN * HH;            // B*N

    hipLaunchKernelGGL(k_proj, dim3(BB * NN / 16), dim3(256), 0, stream,
                       actions, Wq, bq, Wk, bk, Wc, bc, Q, K, PN);
    hipLaunchKernelGGL(k_topk, dim3(BB * (NN / 32)), dim3(256), 0, stream,
                       Q, K, states, incoming);
    hipLaunchKernelGGL(k_coal, dim3(BB * (NN / 32)), dim3(256), 0, stream,
                       PN, incoming, outs);
    hipLaunchKernelGGL(k_mem, dim3(BB * NN / 16), dim3(256), 0, stream,
                       outs, Wh, bh, keys, pos, step, mem, epi, simo);
}

// Round 5
// 626.933 us; speedup vs baseline: 1.2293x; 1.1096x over previous
//
#include <hip/hip_runtime.h>

#define BB 4
#define NN 4096
#define DD 256
#define PP 64
#define HH 1024
#define NCC 256
#define TOPK 8

// ---------------------------------------------------------------------------
// K1: Q = A@Wq+bq, K = A@Wk+bk, proj = A@Wc+bc, pn = proj/max(||proj||,1e-12)
// ---------------------------------------------------------------------------
__global__ __launch_bounds__(256) void k_proj(
    const float* __restrict__ act,
    const float* __restrict__ Wq, const float* __restrict__ bq,
    const float* __restrict__ Wk, const float* __restrict__ bk,
    const float* __restrict__ Wc, const float* __restrict__ bc,
    float* __restrict__ Qo, float* __restrict__ Ko, float* __restrict__ PNo)
{
    __shared__ float As[16][DD];   // 16KB
    __shared__ float Ps[16][PP];   // 4KB
    const int tid = threadIdx.x;
    const long row0 = (long)blockIdx.x * 16;

    {
        const float4* g4 = (const float4*)(act + row0 * DD);
        float4* s4 = (float4*)(&As[0][0]);
#pragma unroll
        for (int i = 0; i < 4; ++i) s4[tid + i * 256] = g4[tid + i * 256];
    }
    __syncthreads();

    const int col = tid & 63;
    const int rg  = tid >> 6;   // 0..3 -> rows rg*4+j
    float aq[4], ak[4], ac[4];
#pragma unroll
    for (int j = 0; j < 4; ++j) { aq[j] = bq[col]; ak[j] = bk[col]; ac[j] = bc[col]; }

    for (int d = 0; d < DD; ++d) {
        float wq = Wq[d * PP + col];
        float wk = Wk[d * PP + col];
        float wc = Wc[d * PP + col];
#pragma unroll
        for (int j = 0; j < 4; ++j) {
            float a = As[rg * 4 + j][d];
            aq[j] = fmaf(a, wq, aq[j]);
            ak[j] = fmaf(a, wk, ak[j]);
            ac[j] = fmaf(a, wc, ac[j]);
        }
    }
#pragma unroll
    for (int j = 0; j < 4; ++j) {
        long r = row0 + rg * 4 + j;
        Qo[r * PP + col] = aq[j];
        Ko[r * PP + col] = ak[j];
        Ps[rg * 4 + j][col] = ac[j];
    }
    __syncthreads();

    const int w = tid >> 6;
    const int lane = tid & 63;
#pragma unroll
    for (int j = 0; j < 4; ++j) {
        int r = w * 4 + j;
        float v = Ps[r][lane];
        float ss = v * v;
#pragma unroll
        for (int off = 32; off >= 1; off >>= 1) ss += __shfl_xor(ss, off, 64);
        float nrm = fmaxf(sqrtf(ss), 1e-12f);
        PNo[(row0 + r) * PP + lane] = v / nrm;
    }
}

// ---------------------------------------------------------------------------
// K2: scores = Q K^T -> per-row top-8 -> softmax -> incoming gather.
// 40KB LDS (no merge union) -> 4 blocks/CU. Branchless sorted-desc insert.
// Final merge: in-register half-wave shfl_xor extraction (row rr lives in
// the 32 contiguous threads tid in [32*(rr&7), 32*(rr&7)+31]).
// ---------------------------------------------------------------------------
__global__ __launch_bounds__(256, 4) void k_topk(
    const float* __restrict__ Q, const float* __restrict__ K,
    const float* __restrict__ states, float* __restrict__ incoming)
{
    __shared__ float Qs[32][PP];       // 8KB
    __shared__ float4 Ks4[128 * 16];   // 32KB, XOR-swizzled float4 slots

    const int tid = threadIdx.x;
    const int b  = blockIdx.x >> 7;
    const int n0 = (blockIdx.x & 127) << 5;

    {
        const float4* g4 = (const float4*)(Q + ((long)b * NN + n0) * PP);
        float4* s4 = (float4*)(&Qs[0][0]);
        s4[tid] = g4[tid];
        s4[tid + 256] = g4[tid + 256];
    }

    const int mg = tid & 31;        // m sub-index (lane within half-wave)
    const int rg = tid >> 5;        // 0..7 -> rows rg+8j
    const int m15 = mg & 15;
    // sorted descending: topv[j][0] >= ... >= topv[j][7]
    float topv[4][TOPK];
    int   topi[4][TOPK];
#pragma unroll
    for (int j = 0; j < 4; ++j)
#pragma unroll
        for (int t = 0; t < TOPK; ++t) { topv[j][t] = -1e30f; topi[j][t] = 0; }

    for (int mt = 0; mt < NN / 128; ++mt) {
        const int m0 = mt << 7;
        __syncthreads();
        {
            const float4* g4 = (const float4*)(K + ((long)b * NN + m0) * PP);
#pragma unroll
            for (int t = 0; t < 8; ++t) {
                int q = tid + t * 256;                 // 0..2047 float4s
                int row = q >> 4, sl = q & 15;
                Ks4[(row << 4) | (sl ^ (row & 15))] = g4[q];
            }
        }
        __syncthreads();

        float s[4][4];
#pragma unroll
        for (int j = 0; j < 4; ++j)
#pragma unroll
            for (int k = 0; k < 4; ++k) s[j][k] = 0.f;

#pragma unroll 4
        for (int sl = 0; sl < 16; ++sl) {              // p = 4*sl
            const int sw = sl ^ m15;
            float4 qv[4], kv[4];
#pragma unroll
            for (int j = 0; j < 4; ++j) qv[j] = *(const float4*)(&Qs[rg + 8 * j][sl << 2]);
#pragma unroll
            for (int k = 0; k < 4; ++k) kv[k] = Ks4[((mg + 32 * k) << 4) + sw];
#pragma unroll
            for (int j = 0; j < 4; ++j)
#pragma unroll
                for (int k = 0; k < 4; ++k) {
                    s[j][k] = fmaf(qv[j].x, kv[k].x, s[j][k]);
                    s[j][k] = fmaf(qv[j].y, kv[k].y, s[j][k]);
                    s[j][k] = fmaf(qv[j].z, kv[k].z, s[j][k]);
                    s[j][k] = fmaf(qv[j].w, kv[k].w, s[j][k]);
                }
        }

        // branchless sorted-desc insert (equal vals keep earlier/lower idx above)
#pragma unroll
        for (int j = 0; j < 4; ++j) {
#pragma unroll
            for (int k = 0; k < 4; ++k) {
                float val = s[j][k];
                int idx = m0 + mg + 32 * k;
                if (val > topv[j][TOPK - 1]) {
                    bool c[TOPK];
#pragma unroll
                    for (int t = 0; t < TOPK; ++t) c[t] = (val > topv[j][t]);
#pragma unroll
                    for (int t = TOPK - 1; t >= 1; --t) {
                        topv[j][t] = c[t - 1] ? topv[j][t - 1] : (c[t] ? val : topv[j][t]);
                        topi[j][t] = c[t - 1] ? topi[j][t - 1] : (c[t] ? idx : topi[j][t]);
                    }
                    topv[j][0] = c[0] ? val : topv[j][0];
                    topi[j][0] = c[0] ? idx : topi[j][0];
                }
            }
        }
    }

    // ---- in-register merge within each half-wave (32 lanes share row rr) ----
#pragma unroll
    for (int j = 0; j < 4; ++j) {
        const int rr = rg + 8 * j;
        float wv[TOPK]; int wi[TOPK];
#pragma unroll
        for (int e = 0; e < TOPK; ++e) {
            float lv = topv[j][0]; int li = topi[j][0];
#pragma unroll
            for (int off = 16; off >= 1; off >>= 1) {
                float ov = __shfl_xor(lv, off, 64);
                int   oi = __shfl_xor(li, off, 64);
                bool tk = (ov > lv) || (ov == lv && oi < li);
                lv = tk ? ov : lv;
                li = tk ? oi : li;
            }
            wv[e] = lv; wi[e] = li;
            bool pop = (topv[j][0] == lv) && (topi[j][0] == li);
#pragma unroll
            for (int t = 0; t < TOPK - 1; ++t) {
                topv[j][t] = pop ? topv[j][t + 1] : topv[j][t];
                topi[j][t] = pop ? topi[j][t + 1] : topi[j][t];
            }
            topv[j][TOPK - 1] = pop ? -1e30f : topv[j][TOPK - 1];
            topi[j][TOPK - 1] = pop ? 0x7FFFFFFF : topi[j][TOPK - 1];
        }

        // softmax over the 8 (wv[0] is the max), then gather by half-wave
        float mx = wv[0] * 0.125f;
        float ex[TOPK]; float Z = 0.f;
#pragma unroll
        for (int e = 0; e < TOPK; ++e) { ex[e] = expf(wv[e] * 0.125f - mx); Z += ex[e]; }
        float invZ = 1.0f / Z;

        float4 a0 = {0.f, 0.f, 0.f, 0.f}, a1 = {0.f, 0.f, 0.f, 0.f};
#pragma unroll
        for (int e = 0; e < TOPK; ++e) {
            const float4* sp = (const float4*)(states + ((long)b * NN + wi[e]) * DD);
            float4 s0 = sp[mg];
            float4 s1 = sp[mg + 32];
            float we = ex[e] * invZ;
            a0.x = fmaf(we, s0.x, a0.x); a0.y = fmaf(we, s0.y, a0.y);
            a0.z = fmaf(we, s0.z, a0.z); a0.w = fmaf(we, s0.w, a0.w);
            a1.x = fmaf(we, s1.x, a1.x); a1.y = fmaf(we, s1.y, a1.y);
            a1.z = fmaf(we, s1.z, a1.z); a1.w = fmaf(we, s1.w, a1.w);
        }
        float4* op = (float4*)(incoming + ((long)b * NN + n0 + rr) * DD);
        op[mg] = a0;
        op[mg + 32] = a1;
    }
}

// ---------------------------------------------------------------------------
// K3: sim = pn pn^T; cmask = sim>0.7; combined; out = 0.8*inc + 0.2*combined
// ---------------------------------------------------------------------------
#define CAP 64
__global__ __launch_bounds__(256, 3) void k_coal(
    const float* __restrict__ PN, const float* __restrict__ incoming,
    float* __restrict__ outs)
{
    __shared__ float Qs[32][PP];        // 8KB
    __shared__ float4 Ks4[128 * 16];    // 32KB, swizzled
    __shared__ int cnt[32];
    __shared__ unsigned short lst[32][CAP];   // 4KB

    const int tid = threadIdx.x;
    const int b  = blockIdx.x >> 7;
    const int n0 = (blockIdx.x & 127) << 5;

    if (tid < 32) cnt[tid] = 0;
    {
        const float4* g4 = (const float4*)(PN + ((long)b * NN + n0) * PP);
        float4* s4 = (float4*)(&Qs[0][0]);
        s4[tid] = g4[tid];
        s4[tid + 256] = g4[tid + 256];
    }

    const int mg = tid & 31;
    const int rg = tid >> 5;
    const int m15 = mg & 15;

    for (int mt = 0; mt < NN / 128; ++mt) {
        const int m0 = mt << 7;
        __syncthreads();
        {
            const float4* g4 = (const float4*)(PN + ((long)b * NN + m0) * PP);
#pragma unroll
            for (int t = 0; t < 8; ++t) {
                int q = tid + t * 256;
                int row = q >> 4, sl = q & 15;
                Ks4[(row << 4) | (sl ^ (row & 15))] = g4[q];
            }
        }
        __syncthreads();

        float s[4][4];
#pragma unroll
        for (int j = 0; j < 4; ++j)
#pragma unroll
            for (int k = 0; k < 4; ++k) s[j][k] = 0.f;

#pragma unroll 4
        for (int sl = 0; sl < 16; ++sl) {
            const int sw = sl ^ m15;
            float4 qv[4], kv[4];
#pragma unroll
            for (int j = 0; j < 4; ++j) qv[j] = *(const float4*)(&Qs[rg + 8 * j][sl << 2]);
#pragma unroll
            for (int k = 0; k < 4; ++k) kv[k] = Ks4[((mg + 32 * k) << 4) + sw];
#pragma unroll
            for (int j = 0; j < 4; ++j)
#pragma unroll
                for (int k = 0; k < 4; ++k) {
                    s[j][k] = fmaf(qv[j].x, kv[k].x, s[j][k]);
                    s[j][k] = fmaf(qv[j].y, kv[k].y, s[j][k]);
                    s[j][k] = fmaf(qv[j].z, kv[k].z, s[j][k]);
                    s[j][k] = fmaf(qv[j].w, kv[k].w, s[j][k]);
                }
        }

#pragma unroll
        for (int j = 0; j < 4; ++j)
#pragma unroll
            for (int k = 0; k < 4; ++k) {
                if (s[j][k] > 0.7f) {
                    int pos = atomicAdd(&cnt[rg + 8 * j], 1);
                    if (pos < CAP) lst[rg + 8 * j][pos] = (unsigned short)(m0 + mg + 32 * k);
                }
            }
    }
    __syncthreads();

    const int w = tid >> 6;
    const int lane = tid & 63;
    for (int rr = w * 8; rr < w * 8 + 8; ++rr) {
        int c = cnt[rr];
        float inv = 1.0f / ((float)c + 1e-8f);
        int cc = (c < CAP) ? c : CAP;
        float ax = 0.f, ay = 0.f, az = 0.f, aw = 0.f;
        for (int i = 0; i < cc; ++i) {
            const float4* ip = (const float4*)(incoming + ((long)b * NN + lst[rr][i]) * DD);
            float4 v = ip[lane];
            ax += v.x; ay += v.y; az += v.z; aw += v.w;
        }
        const float4* self4 = (const float4*)(incoming + ((long)b * NN + n0 + rr) * DD);
        float4 sv = self4[lane];
        float4 o;
        o.x = 0.8f * sv.x + 0.2f * inv * ax;
        o.y = 0.8f * sv.y + 0.2f * inv * ay;
        o.z = 0.8f * sv.z + 0.2f * inv * az;
        o.w = 0.8f * sv.w + 0.2f * inv * aw;
        ((float4*)(outs + ((long)b * NN + n0 + rr) * DD))[lane] = o;
    }
}

// ---------------------------------------------------------------------------
// K4: hdc = tanh(3(out@Wh+bh)); bind; decay-write; cosine read.
// ---------------------------------------------------------------------------
__global__ __launch_bounds__(256, 2) void k_mem(
    const float* __restrict__ outs, const float* __restrict__ Wh,
    const float* __restrict__ bh, const float* __restrict__ keys,
    const float* __restrict__ pos_codes, const int* __restrict__ stepp,
    const float* __restrict__ mem,
    float* __restrict__ epi_out, float* __restrict__ sim_out)
{
    __shared__ float Ss[16][DD];    // 16KB
    __shared__ float Wt[8][HH];     // 32KB
    __shared__ float red[4][8][3];

    const int tid = threadIdx.x;
    const long row0 = (long)blockIdx.x * 16;

    {
        const float4* g4 = (const float4*)(outs + row0 * DD);
        float4* s4 = (float4*)(&Ss[0][0]);
#pragma unroll
        for (int i = 0; i < 4; ++i) s4[tid + i * 256] = g4[tid + i * 256];
    }

    const int hg = tid & 127;       // h = hg + 128k
    const int rg = tid >> 7;        // rows rg*8+j
    float acc[8][8];
#pragma unroll
    for (int j = 0; j < 8; ++j)
#pragma unroll
        for (int k = 0; k < 8; ++k) acc[j][k] = 0.f;

    for (int dt = 0; dt < DD / 8; ++dt) {
        __syncthreads();
        {
            const float4* g4 = (const float4*)(Wh + (long)dt * 8 * HH);
            float4* s4 = (float4*)(&Wt[0][0]);
#pragma unroll
            for (int t = 0; t < 8; ++t) s4[tid + t * 256] = g4[tid + t * 256];
        }
        __syncthreads();
#pragma unroll
        for (int dq = 0; dq < 2; ++dq) {
            float sv[8][4];
#pragma unroll
            for (int j = 0; j < 8; ++j) {
                float4 t4 = *(const float4*)(&Ss[rg * 8 + j][dt * 8 + dq * 4]);
                sv[j][0] = t4.x; sv[j][1] = t4.y; sv[j][2] = t4.z; sv[j][3] = t4.w;
            }
#pragma unroll
            for (int d2 = 0; d2 < 4; ++d2) {
                float wvv[8];
#pragma unroll
                for (int k = 0; k < 8; ++k) wvv[k] = Wt[dq * 4 + d2][hg + 128 * k];
#pragma unroll
                for (int j = 0; j < 8; ++j)
#pragma unroll
                    for (int k = 0; k < 8; ++k)
                        acc[j][k] = fmaf(sv[j][d2], wvv[k], acc[j][k]);
            }
        }
    }

    const int step = stepp[0];
    const int prow = ((step % NCC) + NCC) % NCC;
    float dnp[8], dnn[8], dpp[8];
#pragma unroll
    for (int j = 0; j < 8; ++j) { dnp[j] = 0.f; dnn[j] = 0.f; dpp[j] = 0.f; }

#pragma unroll
    for (int k = 0; k < 8; ++k) {
        int h = hg + 128 * k;
        float ps = pos_codes[(long)prow * HH + h];
        float bb = bh[h];
#pragma unroll
        for (int j = 0; j < 8; ++j) {
            long row = row0 + rg * 8 + j;
            int n = (int)(row & (NN - 1));
            float y = acc[j][k] + bb;
            float hd = tanhf(3.0f * y);
            float per = hd * keys[(long)n * HH + h];
            float bound = per * ps;
            float ne = 0.95f * mem[row * HH + h] + 0.05f * bound;
            epi_out[row * HH + h] = ne;
            dnp[j] = fmaf(ne, per, dnp[j]);
            dnn[j] = fmaf(ne, ne, dnn[j]);
            dpp[j] = fmaf(per, per, dpp[j]);
        }
    }

#pragma unroll
    for (int j = 0; j < 8; ++j) {
#pragma unroll
        for (int off = 32; off >= 1; off >>= 1) {
            dnp[j] += __shfl_xor(dnp[j], off, 64);
            dnn[j] += __shfl_xor(dnn[j], off, 64);
            dpp[j] += __shfl_xor(dpp[j], off, 64);
        }
    }
    const int w = tid >> 6;
    const int lane = tid & 63;
    if (lane == 0) {
#pragma unroll
        for (int j = 0; j < 8; ++j) {
            red[w][j][0] = dnp[j]; red[w][j][1] = dnn[j]; red[w][j][2] = dpp[j];
        }
    }
    __syncthreads();
    if (tid < 16) {
        int rgp = tid >> 3, j = tid & 7;
        float dot = red[rgp * 2][j][0] + red[rgp * 2 + 1][j][0];
        float nn  = red[rgp * 2][j][1] + red[rgp * 2 + 1][j][1];
        float pp  = red[rgp * 2][j][2] + red[rgp * 2 + 1][j][2];
        float na = fmaxf(sqrtf(nn), 1e-8f);
        float nb = fmaxf(sqrtf(pp), 1e-8f);
        sim_out[row0 + rgp * 8 + j] = dot / (na * nb);
    }
}

// ---------------------------------------------------------------------------
extern "C" void kernel_launch(void* const* d_in, const int* in_sizes, int n_in,
                              void* d_out, int out_size, void* d_ws, size_t ws_size,
                              hipStream_t stream)
{
    const float* states  = (const float*)d_in[0];
    const float* actions = (const float*)d_in[1];
    const float* mem     = (const float*)d_in[2];
    const float* Wq = (const float*)d_in[3];
    const float* bq = (const float*)d_in[4];
    const float* Wk = (const float*)d_in[5];
    const float* bk = (const float*)d_in[6];
    const float* Wc = (const float*)d_in[7];
    const float* bc = (const float*)d_in[8];
    const float* Wh = (const float*)d_in[9];
    const float* bh = (const float*)d_in[10];
    const float* keys = (const float*)d_in[11];
    const float* pos  = (const float*)d_in[12];
    const int*   step = (const int*)d_in[13];

    float* ws = (float*)d_ws;
    float* Q        = ws;                    // 1,048,576 floats
    float* K        = ws + 1048576;          // 1,048,576
    float* PN       = ws + 2097152;          // 1,048,576
    float* incoming = ws + 3145728;          // 4,194,304

    float* outs = (float*)d_out;                       // B*N*D
    float* epi  = outs + (long)BB * NN * DD;           // B*N*H
    float* simo = epi + (long)BB * NN * HH;            // B*N

    hipLaunchKernelGGL(k_proj, dim3(BB * NN / 16), dim3(256), 0, stream,
                       actions, Wq, bq, Wk, bk, Wc, bc, Q, K, PN);
    hipLaunchKernelGGL(k_topk, dim3(BB * (NN / 32)), dim3(256), 0, stream,
                       Q, K, states, incoming);
    hipLaunchKernelGGL(k_coal, dim3(BB * (NN / 32)), dim3(256), 0, stream,
                       PN, incoming, outs);
    hipLaunchKernelGGL(k_mem, dim3(BB * NN / 16), dim3(256), 0, stream,
                       outs, Wh, bh, keys, pos, step, mem, epi, simo);
}